// Round 5
// baseline (367.483 us; speedup 1.0000x reference)
//
#include <hip/hip_runtime.h>
#include <hip/hip_bf16.h>

// B=4, N=1024, C=768, H=12, D=64, SCALE=1/8. Inputs fp32, output fp32.
// Internal math bf16 MFMA. fp32->bf16 pre-convert enables global_load_lds(16B).

typedef __bf16 bf16x8 __attribute__((ext_vector_type(8)));
typedef float  f32x4  __attribute__((ext_vector_type(4)));

__device__ __forceinline__ bf16x8 cvt8(const float* p) {
    f32x4 f0 = *(const f32x4*)p;
    f32x4 f1 = *(const f32x4*)(p + 4);
    bf16x8 r;
    r[0] = (__bf16)f0[0]; r[1] = (__bf16)f0[1]; r[2] = (__bf16)f0[2]; r[3] = (__bf16)f0[3];
    r[4] = (__bf16)f1[0]; r[5] = (__bf16)f1[1]; r[6] = (__bf16)f1[2]; r[7] = (__bf16)f1[3];
    return r;
}

__device__ __forceinline__ void async16(const __bf16* g, __bf16* l) {
    __builtin_amdgcn_global_load_lds(
        (const __attribute__((address_space(1))) void*)g,
        (__attribute__((address_space(3))) void*)l, 16, 0, 0);
}

// ---------------------------------------------------------------------------
// fp32 -> bf16 convert, 8 elems/thread
// ---------------------------------------------------------------------------
__global__ __launch_bounds__(256)
void cvt_k(const float* __restrict__ src, __bf16* __restrict__ dst, int n) {
    int i = (blockIdx.x * 256 + threadIdx.x) * 8;
    if (i < n) *(bf16x8*)(dst + i) = cvt8(src + i);
}

// ---------------------------------------------------------------------------
// 128x128-tile QKV GEMM (m97 structure). q,k -> [2,B,H,N,D] (q/8), v -> [2,B,H,D,N]
// ---------------------------------------------------------------------------
__global__ __launch_bounds__(256)
void gemm_qkv_s(const __bf16* __restrict__ A, const __bf16* __restrict__ Wq,
                const float* __restrict__ bias,
                __bf16* __restrict__ qo, __bf16* __restrict__ ko,
                __bf16* __restrict__ vo, int st)
{
    constexpr int K = 768;
    __shared__ __bf16 As[128 * 32];
    __shared__ __bf16 Bs[128 * 32];

    const int t = threadIdx.x, w = t >> 6, lane = t & 63;
    const int l15 = lane & 15, quad = lane >> 4;
    const int wm = w >> 1, wn = w & 1;
    const int gx = blockIdx.x, gy = blockIdx.y;
    const int lrow = lane >> 2, lcol = (lane & 3) * 8;

    const __bf16* Ab = A  + (size_t)(gy * 128) * K;
    const __bf16* Bb = Wq + (size_t)(gx * 128) * K;

    f32x4 acc[4][4];
#pragma unroll
    for (int mi = 0; mi < 4; mi++)
#pragma unroll
        for (int ni = 0; ni < 4; ni++) acc[mi][ni] = f32x4{0.f, 0.f, 0.f, 0.f};

    for (int k0 = 0; k0 < K; k0 += 32) {
#pragma unroll
        for (int i = 0; i < 2; i++) {
            int r = w * 32 + i * 16 + lrow;
            async16(Ab + (size_t)r * K + k0 + lcol, &As[r * 32 + lcol]);
            async16(Bb + (size_t)r * K + k0 + lcol, &Bs[r * 32 + lcol]);
        }
        __syncthreads();
        bf16x8 af[4], bfr[4];
#pragma unroll
        for (int mi = 0; mi < 4; mi++)
            af[mi] = *(const bf16x8*)&As[(wm * 64 + mi * 16 + l15) * 32 + quad * 8];
#pragma unroll
        for (int ni = 0; ni < 4; ni++)
            bfr[ni] = *(const bf16x8*)&Bs[(wn * 64 + ni * 16 + l15) * 32 + quad * 8];
#pragma unroll
        for (int mi = 0; mi < 4; mi++)
#pragma unroll
            for (int ni = 0; ni < 4; ni++)
                acc[mi][ni] = __builtin_amdgcn_mfma_f32_16x16x32_bf16(af[mi], bfr[ni], acc[mi][ni], 0, 0, 0);
        __syncthreads();
    }

#pragma unroll
    for (int ni = 0; ni < 4; ni++) {
        int j     = gx * 128 + wn * 64 + ni * 16 + l15;   // 0..2303
        int which = j / 768;
        int c     = j - which * 768;
        int h = c >> 6, d = c & 63;
        float bj  = bias[j];
#pragma unroll
        for (int mi = 0; mi < 4; mi++) {
#pragma unroll
            for (int r = 0; r < 4; r++) {
                int row = gy * 128 + wm * 64 + mi * 16 + quad * 4 + r;  // 0..4095
                int b = row >> 10, tok = row & 1023;
                float val = acc[mi][ni][r] + bj;
                if (which == 0)
                    qo[((size_t)((st * 4 + b) * 12 + h) * 1024 + tok) * 64 + d] = (__bf16)(val * 0.125f);
                else if (which == 1)
                    ko[((size_t)((st * 4 + b) * 12 + h) * 1024 + tok) * 64 + d] = (__bf16)val;
                else
                    vo[((size_t)((st * 4 + b) * 12 + h) * 64 + d) * 1024 + tok] = (__bf16)val;
            }
        }
    }
}

// ---------------------------------------------------------------------------
// 128x128-tile proj GEMM: A bf16 [8192x768], W bf16 [768x768], out fp32 + bias
// ---------------------------------------------------------------------------
__global__ __launch_bounds__(256)
void gemm_proj(const __bf16* __restrict__ A, const __bf16* __restrict__ Wp,
               const float* __restrict__ bias, float* __restrict__ out)
{
    constexpr int K = 768;
    __shared__ __bf16 As[128 * 32];
    __shared__ __bf16 Bs[128 * 32];

    const int t = threadIdx.x, w = t >> 6, lane = t & 63;
    const int l15 = lane & 15, quad = lane >> 4;
    const int wm = w >> 1, wn = w & 1;
    const int gx = blockIdx.x, gy = blockIdx.y;
    const int lrow = lane >> 2, lcol = (lane & 3) * 8;

    const __bf16* Ab = A  + (size_t)(gy * 128) * K;
    const __bf16* Bb = Wp + (size_t)(gx * 128) * K;

    f32x4 acc[4][4];
#pragma unroll
    for (int mi = 0; mi < 4; mi++)
#pragma unroll
        for (int ni = 0; ni < 4; ni++) acc[mi][ni] = f32x4{0.f, 0.f, 0.f, 0.f};

    for (int k0 = 0; k0 < K; k0 += 32) {
#pragma unroll
        for (int i = 0; i < 2; i++) {
            int r = w * 32 + i * 16 + lrow;
            async16(Ab + (size_t)r * K + k0 + lcol, &As[r * 32 + lcol]);
            async16(Bb + (size_t)r * K + k0 + lcol, &Bs[r * 32 + lcol]);
        }
        __syncthreads();
        bf16x8 af[4], bfr[4];
#pragma unroll
        for (int mi = 0; mi < 4; mi++)
            af[mi] = *(const bf16x8*)&As[(wm * 64 + mi * 16 + l15) * 32 + quad * 8];
#pragma unroll
        for (int ni = 0; ni < 4; ni++)
            bfr[ni] = *(const bf16x8*)&Bs[(wn * 64 + ni * 16 + l15) * 32 + quad * 8];
#pragma unroll
        for (int mi = 0; mi < 4; mi++)
#pragma unroll
            for (int ni = 0; ni < 4; ni++)
                acc[mi][ni] = __builtin_amdgcn_mfma_f32_16x16x32_bf16(af[mi], bfr[ni], acc[mi][ni], 0, 0, 0);
        __syncthreads();
    }

#pragma unroll
    for (int ni = 0; ni < 4; ni++) {
        int col  = gx * 128 + wn * 64 + ni * 16 + l15;
        float bj = bias[col];
#pragma unroll
        for (int mi = 0; mi < 4; mi++)
#pragma unroll
            for (int r = 0; r < 4; r++) {
                int row = gy * 128 + wm * 64 + mi * 16 + quad * 4 + r;  // 0..8191
                out[(size_t)row * 768 + col] = acc[mi][ni][r] + bj;
            }
    }
}

// ---------------------------------------------------------------------------
// Barrier-free dual-stream flash attention.
// Grid (16 q-tiles, 48 b*h), 256 thr = 4 independent waves; wave owns 16 q-rows.
// S^T = K @ Q^T: A-frag = K direct from global (b128), B-frag = Q regs.
//   C-layout of S^T: col(l15)=q, row(quad*4+reg)=key -> softmax reduction over
//   keys = 16 in-lane ops + shfl_xor(16) + shfl_xor(32). State (m,l) lane-idx by q.
// P[q][key] -> per-wave Ps LDS (intra-wave, NO barrier), read as A-frag b128.
// V B-frags direct from global v_ws[.,D,N] (b128). No __syncthreads anywhere.
// ---------------------------------------------------------------------------
__global__ __launch_bounds__(256)
void attn_k(const __bf16* __restrict__ qws, const __bf16* __restrict__ kws,
            const __bf16* __restrict__ vws, __bf16* __restrict__ ows)
{
    __shared__ __bf16 Ps[4][16 * 72];   // per-wave P tile, 2.3 KB each

    const int qt = blockIdx.x;          // 0..15
    const int bh = blockIdx.y;          // 0..47
    const int b = bh / 12, h = bh % 12;
    const int t = threadIdx.x, w = t >> 6, lane = t & 63;
    const int l15 = lane & 15, quad = lane >> 4;

    const size_t head_off = (size_t)bh * 65536;          // 1024*64
    const size_t ss       = (size_t)48 * 65536;          // stream stride

    // Q^T B-frags: lane n=l15 -> q-row (qt*64 + w*16 + l15), k=quad*8+j -> d
    bf16x8 qf[2][2];
#pragma unroll
    for (int s = 0; s < 2; s++)
#pragma unroll
        for (int kk = 0; kk < 2; kk++)
            qf[s][kk] = *(const bf16x8*)(qws + s * ss + head_off
                          + (size_t)(qt * 64 + w * 16 + l15) * 64 + kk * 32 + quad * 8);

    float m_prev = -1e30f, l_run = 0.f;   // per-lane state for q = (own l15)
    f32x4 accO[2][4];
#pragma unroll
    for (int s = 0; s < 2; s++)
#pragma unroll
        for (int ni = 0; ni < 4; ni++) accO[s][ni] = f32x4{0.f, 0.f, 0.f, 0.f};

    const __bf16* kbase = kws + head_off;
    const __bf16* vbase = vws + head_off;

    for (int kt = 0; kt < 16; kt++) {
        // ---- S^T = sum_s K_s @ Q_s^T  (rows=keys, cols=q) ----
        f32x4 accS[4];
#pragma unroll
        for (int i = 0; i < 4; i++) accS[i] = f32x4{0.f, 0.f, 0.f, 0.f};
#pragma unroll
        for (int s = 0; s < 2; s++)
#pragma unroll
            for (int kk = 0; kk < 2; kk++) {
                bf16x8 kf[4];
#pragma unroll
                for (int mi = 0; mi < 4; mi++)
                    kf[mi] = *(const bf16x8*)(kbase + s * ss
                               + (size_t)(kt * 64 + mi * 16 + l15) * 64 + kk * 32 + quad * 8);
#pragma unroll
                for (int mi = 0; mi < 4; mi++)
                    accS[mi] = __builtin_amdgcn_mfma_f32_16x16x32_bf16(kf[mi], qf[s][kk], accS[mi], 0, 0, 0);
            }

        // ---- online softmax over keys (regs+quads), per q-column (l15) ----
        float mx = accS[0][0];
#pragma unroll
        for (int mi = 0; mi < 4; mi++)
#pragma unroll
            for (int r = 0; r < 4; r++) mx = fmaxf(mx, accS[mi][r]);
        mx = fmaxf(mx, __shfl_xor(mx, 16));
        mx = fmaxf(mx, __shfl_xor(mx, 32));
        float mnew  = fmaxf(m_prev, mx);
        float alpha = __expf(m_prev - mnew);
        float p[4][4], rs = 0.f;
#pragma unroll
        for (int mi = 0; mi < 4; mi++)
#pragma unroll
            for (int r = 0; r < 4; r++) {
                float pv = __expf(accS[mi][r] - mnew);
                p[mi][r] = pv;
                rs += pv;
            }
        rs += __shfl_xor(rs, 16);
        rs += __shfl_xor(rs, 32);
        l_run  = l_run * alpha + rs;
        m_prev = mnew;

        // alpha lives lane-indexed (q=l15); accO rows are reg-indexed (q=quad*4+r)
        float alr[4];
#pragma unroll
        for (int r = 0; r < 4; r++) alr[r] = __shfl(alpha, quad * 4 + r);
#pragma unroll
        for (int s = 0; s < 2; s++)
#pragma unroll
            for (int ni = 0; ni < 4; ni++)
#pragma unroll
                for (int r = 0; r < 4; r++) accO[s][ni][r] *= alr[r];

        // ---- P[q][key] to per-wave LDS (intra-wave only; no barrier) ----
#pragma unroll
        for (int mi = 0; mi < 4; mi++)
#pragma unroll
            for (int r = 0; r < 4; r++)
                Ps[w][l15 * 72 + mi * 16 + quad * 4 + r] = (__bf16)p[mi][r];

        // ---- O_s += P @ V_s (A-frag from Ps, B-frag direct from v_ws[.,D,N]) ----
#pragma unroll
        for (int kk = 0; kk < 2; kk++) {
            bf16x8 pa = *(const bf16x8*)&Ps[w][l15 * 72 + kk * 32 + quad * 8];
#pragma unroll
            for (int s = 0; s < 2; s++)
#pragma unroll
                for (int ni = 0; ni < 4; ni++) {
                    bf16x8 vf = *(const bf16x8*)(vbase + s * ss
                                  + (size_t)(ni * 16 + l15) * 1024 + kt * 64 + kk * 32 + quad * 8);
                    accO[s][ni] = __builtin_amdgcn_mfma_f32_16x16x32_bf16(pa, vf, accO[s][ni], 0, 0, 0);
                }
        }
    }

    // Epilogue: accO C-layout: col(l15)=d-part, row(quad*4+r)=q. l_run is lane-idx.
    float il = 1.f / l_run;
    float ilr[4];
#pragma unroll
    for (int r = 0; r < 4; r++) ilr[r] = __shfl(il, quad * 4 + r);
#pragma unroll
    for (int r = 0; r < 4; r++) {
        int tok = qt * 64 + w * 16 + quad * 4 + r;
#pragma unroll
        for (int s = 0; s < 2; s++)
#pragma unroll
            for (int ni = 0; ni < 4; ni++) {
                size_t idx = ((size_t)((s * 4 + b) * 1024 + tok)) * 768 + h * 64 + ni * 16 + l15;
                ows[idx] = (__bf16)(accO[s][ni][r] * ilr[r]);
            }
    }
}

// ---------------------------------------------------------------------------
extern "C" void kernel_launch(void* const* d_in, const int* in_sizes, int n_in,
                              void* d_out, int out_size, void* d_ws, size_t ws_size,
                              hipStream_t stream)
{
    const float* x1    = (const float*)d_in[0];
    const float* x2    = (const float*)d_in[1];
    const float* Wqkv  = (const float*)d_in[2];
    const float* bqkv  = (const float*)d_in[3];
    const float* Wproj = (const float*)d_in[4];
    const float* bproj = (const float*)d_in[5];
    float* out = (float*)d_out;

    // ws: q | k | v | pool   (4 x 6291456 bf16 = 50.33 MB, proven footprint)
    const size_t qkv_elems = (size_t)2 * 4 * 12 * 1024 * 64;   // 6,291,456
    __bf16* q_ws = (__bf16*)d_ws;
    __bf16* k_ws = q_ws + qkv_elems;
    __bf16* v_ws = k_ws + qkv_elems;
    __bf16* pool = v_ws + qkv_elems;
    __bf16* Xc  = pool;                 // 4096*768 = 3,145,728
    __bf16* Wqc = pool + 3145728;       // 2304*768 = 1,769,472
    __bf16* o_ws = pool;                // 8192*768 = 6,291,456 (after QKV)
    __bf16* Wpc = q_ws;                 // 768*768 (q dead after attn)

    // stream 0
    cvt_k<<<1536, 256, 0, stream>>>(x1, Xc, 3145728);
    cvt_k<<<864,  256, 0, stream>>>(Wqkv, Wqc, 1769472);
    gemm_qkv_s<<<dim3(18, 32), 256, 0, stream>>>(Xc, Wqc, bqkv, q_ws, k_ws, v_ws, 0);
    // stream 1 (Xc reused)
    cvt_k<<<1536, 256, 0, stream>>>(x2, Xc, 3145728);
    gemm_qkv_s<<<dim3(18, 32), 256, 0, stream>>>(Xc, Wqc, bqkv, q_ws, k_ws, v_ws, 1);
    // attention (barrier-free)
    attn_k<<<dim3(16, 48), 256, 0, stream>>>(q_ws, k_ws, v_ws, o_ws);
    // proj
    cvt_k<<<288, 256, 0, stream>>>(Wproj, Wpc, 589824);
    gemm_proj<<<dim3(6, 64), 256, 0, stream>>>(o_ws, Wpc, bproj, out);
}

// Round 6
// 250.063 us; speedup vs baseline: 1.4696x; 1.4696x over previous
//
#include <hip/hip_runtime.h>
#include <hip/hip_bf16.h>

// B=4, N=1024, C=768, H=12, D=64, SCALE=1/8. Inputs fp32, output fp32.
// Internal math bf16 MFMA. fp32->bf16 pre-convert enables global_load_lds(16B).

typedef __bf16 bf16x8 __attribute__((ext_vector_type(8)));
typedef float  f32x4  __attribute__((ext_vector_type(4)));

__device__ __forceinline__ bf16x8 cvt8(const float* p) {
    f32x4 f0 = *(const f32x4*)p;
    f32x4 f1 = *(const f32x4*)(p + 4);
    bf16x8 r;
    r[0] = (__bf16)f0[0]; r[1] = (__bf16)f0[1]; r[2] = (__bf16)f0[2]; r[3] = (__bf16)f0[3];
    r[4] = (__bf16)f1[0]; r[5] = (__bf16)f1[1]; r[6] = (__bf16)f1[2]; r[7] = (__bf16)f1[3];
    return r;
}

__device__ __forceinline__ void async16(const __bf16* g, __bf16* l) {
    __builtin_amdgcn_global_load_lds(
        (const __attribute__((address_space(1))) void*)g,
        (__attribute__((address_space(3))) void*)l, 16, 0, 0);
}

// ---------------------------------------------------------------------------
// fp32 -> bf16 convert, 8 elems/thread
// ---------------------------------------------------------------------------
__global__ __launch_bounds__(256)
void cvt_k(const float* __restrict__ src, __bf16* __restrict__ dst, int n) {
    int i = (blockIdx.x * 256 + threadIdx.x) * 8;
    if (i < n) *(bf16x8*)(dst + i) = cvt8(src + i);
}

// ---------------------------------------------------------------------------
// 128x128-tile QKV GEMM (m97 structure). q,k -> [2,B,H,N,D] (q/8), v -> [2,B,H,D,N]
// ---------------------------------------------------------------------------
__global__ __launch_bounds__(256)
void gemm_qkv_s(const __bf16* __restrict__ A, const __bf16* __restrict__ Wq,
                const float* __restrict__ bias,
                __bf16* __restrict__ qo, __bf16* __restrict__ ko,
                __bf16* __restrict__ vo, int st)
{
    constexpr int K = 768;
    __shared__ __bf16 As[128 * 32];
    __shared__ __bf16 Bs[128 * 32];

    const int t = threadIdx.x, w = t >> 6, lane = t & 63;
    const int l15 = lane & 15, quad = lane >> 4;
    const int wm = w >> 1, wn = w & 1;
    const int gx = blockIdx.x, gy = blockIdx.y;
    const int lrow = lane >> 2, lcol = (lane & 3) * 8;

    const __bf16* Ab = A  + (size_t)(gy * 128) * K;
    const __bf16* Bb = Wq + (size_t)(gx * 128) * K;

    f32x4 acc[4][4];
#pragma unroll
    for (int mi = 0; mi < 4; mi++)
#pragma unroll
        for (int ni = 0; ni < 4; ni++) acc[mi][ni] = f32x4{0.f, 0.f, 0.f, 0.f};

    for (int k0 = 0; k0 < K; k0 += 32) {
#pragma unroll
        for (int i = 0; i < 2; i++) {
            int r = w * 32 + i * 16 + lrow;
            async16(Ab + (size_t)r * K + k0 + lcol, &As[r * 32 + lcol]);
            async16(Bb + (size_t)r * K + k0 + lcol, &Bs[r * 32 + lcol]);
        }
        __syncthreads();
        bf16x8 af[4], bfr[4];
#pragma unroll
        for (int mi = 0; mi < 4; mi++)
            af[mi] = *(const bf16x8*)&As[(wm * 64 + mi * 16 + l15) * 32 + quad * 8];
#pragma unroll
        for (int ni = 0; ni < 4; ni++)
            bfr[ni] = *(const bf16x8*)&Bs[(wn * 64 + ni * 16 + l15) * 32 + quad * 8];
#pragma unroll
        for (int mi = 0; mi < 4; mi++)
#pragma unroll
            for (int ni = 0; ni < 4; ni++)
                acc[mi][ni] = __builtin_amdgcn_mfma_f32_16x16x32_bf16(af[mi], bfr[ni], acc[mi][ni], 0, 0, 0);
        __syncthreads();
    }

#pragma unroll
    for (int ni = 0; ni < 4; ni++) {
        int j     = gx * 128 + wn * 64 + ni * 16 + l15;   // 0..2303
        int which = j / 768;
        int c     = j - which * 768;
        int h = c >> 6, d = c & 63;
        float bj  = bias[j];
#pragma unroll
        for (int mi = 0; mi < 4; mi++) {
#pragma unroll
            for (int r = 0; r < 4; r++) {
                int row = gy * 128 + wm * 64 + mi * 16 + quad * 4 + r;  // 0..4095
                int b = row >> 10, tok = row & 1023;
                float val = acc[mi][ni][r] + bj;
                if (which == 0)
                    qo[((size_t)((st * 4 + b) * 12 + h) * 1024 + tok) * 64 + d] = (__bf16)(val * 0.125f);
                else if (which == 1)
                    ko[((size_t)((st * 4 + b) * 12 + h) * 1024 + tok) * 64 + d] = (__bf16)val;
                else
                    vo[((size_t)((st * 4 + b) * 12 + h) * 64 + d) * 1024 + tok] = (__bf16)val;
            }
        }
    }
}

// ---------------------------------------------------------------------------
// 128x128-tile proj GEMM: A bf16 [8192x768], W bf16 [768x768], out fp32 + bias
// ---------------------------------------------------------------------------
__global__ __launch_bounds__(256)
void gemm_proj(const __bf16* __restrict__ A, const __bf16* __restrict__ Wp,
               const float* __restrict__ bias, float* __restrict__ out)
{
    constexpr int K = 768;
    __shared__ __bf16 As[128 * 32];
    __shared__ __bf16 Bs[128 * 32];

    const int t = threadIdx.x, w = t >> 6, lane = t & 63;
    const int l15 = lane & 15, quad = lane >> 4;
    const int wm = w >> 1, wn = w & 1;
    const int gx = blockIdx.x, gy = blockIdx.y;
    const int lrow = lane >> 2, lcol = (lane & 3) * 8;

    const __bf16* Ab = A  + (size_t)(gy * 128) * K;
    const __bf16* Bb = Wp + (size_t)(gx * 128) * K;

    f32x4 acc[4][4];
#pragma unroll
    for (int mi = 0; mi < 4; mi++)
#pragma unroll
        for (int ni = 0; ni < 4; ni++) acc[mi][ni] = f32x4{0.f, 0.f, 0.f, 0.f};

    for (int k0 = 0; k0 < K; k0 += 32) {
#pragma unroll
        for (int i = 0; i < 2; i++) {
            int r = w * 32 + i * 16 + lrow;
            async16(Ab + (size_t)r * K + k0 + lcol, &As[r * 32 + lcol]);
            async16(Bb + (size_t)r * K + k0 + lcol, &Bs[r * 32 + lcol]);
        }
        __syncthreads();
        bf16x8 af[4], bfr[4];
#pragma unroll
        for (int mi = 0; mi < 4; mi++)
            af[mi] = *(const bf16x8*)&As[(wm * 64 + mi * 16 + l15) * 32 + quad * 8];
#pragma unroll
        for (int ni = 0; ni < 4; ni++)
            bfr[ni] = *(const bf16x8*)&Bs[(wn * 64 + ni * 16 + l15) * 32 + quad * 8];
#pragma unroll
        for (int mi = 0; mi < 4; mi++)
#pragma unroll
            for (int ni = 0; ni < 4; ni++)
                acc[mi][ni] = __builtin_amdgcn_mfma_f32_16x16x32_bf16(af[mi], bfr[ni], acc[mi][ni], 0, 0, 0);
        __syncthreads();
    }

#pragma unroll
    for (int ni = 0; ni < 4; ni++) {
        int col  = gx * 128 + wn * 64 + ni * 16 + l15;
        float bj = bias[col];
#pragma unroll
        for (int mi = 0; mi < 4; mi++)
#pragma unroll
            for (int r = 0; r < 4; r++) {
                int row = gy * 128 + wm * 64 + mi * 16 + quad * 4 + r;  // 0..8191
                out[(size_t)row * 768 + col] = acc[mi][ni][r] + bj;
            }
    }
}

// ---------------------------------------------------------------------------
// Dual-stream flash attention, fragment-major LDS staging.
// Grid: 768 1-D blocks; g -> qt = g/48, bh = g%48 (qt stride 48 ≡ 0 mod 8 ->
// all q-tiles of a head land on one XCD for K/V L2 reuse).
// Block = 4 waves; wave owns 16 q-rows. S^T = K @ Q^T (A=K frag, B=Q regs):
// softmax over keys = 16 in-lane ops + 2 shuffles; state lane-indexed by q=l15.
// K/V staged via global_load_lds(16B) into fragment-major LDS:
//   KVf[kv][s][kk][mi][lane*8] -- compute reads are lane-linear b128,
//   conflict-free; staging = 8 async16 per wave, zero VALU repack.
// P round-trips per-wave Ps (intra-wave, no barrier). 2 barriers per kt.
// ---------------------------------------------------------------------------
__global__ __launch_bounds__(256)
void attn_k(const __bf16* __restrict__ qws, const __bf16* __restrict__ kws,
            const __bf16* __restrict__ vws, __bf16* __restrict__ ows)
{
    __shared__ __bf16 KVf[2][2][2][4][512];  // [K/V][s][kk][mi][lane*8] = 32 KB
    __shared__ __bf16 Ps[4][16 * 72];        // per-wave P, 9 KB

    const int g  = blockIdx.x;
    const int qt = g / 48;              // 0..15
    const int bh = g % 48;              // 0..47
    const int b = bh / 12, h = bh % 12;
    const int t = threadIdx.x, w = t >> 6, lane = t & 63;
    const int l15 = lane & 15, quad = lane >> 4;

    const size_t head_off = (size_t)bh * 65536;          // 1024*64
    const size_t ss       = (size_t)48 * 65536;          // stream stride

    // Q^T B-frags: lane n=l15 -> q-row (qt*64 + w*16 + l15), k=quad*8+j -> d
    bf16x8 qf[2][2];
#pragma unroll
    for (int s = 0; s < 2; s++)
#pragma unroll
        for (int kk = 0; kk < 2; kk++)
            qf[s][kk] = *(const bf16x8*)(qws + s * ss + head_off
                          + (size_t)(qt * 64 + w * 16 + l15) * 64 + kk * 32 + quad * 8);

    float m_prev = -1e30f, l_run = 0.f;   // per-lane state for q = (own l15)
    f32x4 accO[2][4];
#pragma unroll
    for (int s = 0; s < 2; s++)
#pragma unroll
        for (int ni = 0; ni < 4; ni++) accO[s][ni] = f32x4{0.f, 0.f, 0.f, 0.f};

    const __bf16* kbase = kws + head_off;
    const __bf16* vbase = vws + head_off;

    for (int kt = 0; kt < 16; kt++) {
        __syncthreads();   // prev iteration's frag reads done before restage
        // stage 32 frags (16 K + 16 V), 8 per wave, frag-major LDS
#pragma unroll
        for (int i = 0; i < 8; i++) {
            int f  = w * 8 + i;
            int kv = f >> 4, s = (f >> 3) & 1, kk = (f >> 2) & 1, mi = f & 3;
            const __bf16* gp;
            if (kv == 0)   // K A-frag: lane l -> key=mi*16+(l&15), d=kk*32+(l>>4)*8
                gp = kbase + s * ss + (size_t)(kt * 64 + mi * 16 + l15) * 64
                     + kk * 32 + quad * 8;
            else           // V B-frag: lane l -> d=mi*16+(l&15), key=kt*64+kk*32+(l>>4)*8
                gp = vbase + s * ss + (size_t)(mi * 16 + l15) * 1024
                     + kt * 64 + kk * 32 + quad * 8;
            async16(gp, &KVf[kv][s][kk][mi][lane * 8]);
        }
        __syncthreads();

        // ---- S^T = sum_s K_s @ Q_s^T  (rows=keys, cols=q) ----
        f32x4 accS[4];
#pragma unroll
        for (int i = 0; i < 4; i++) accS[i] = f32x4{0.f, 0.f, 0.f, 0.f};
#pragma unroll
        for (int s = 0; s < 2; s++)
#pragma unroll
            for (int kk = 0; kk < 2; kk++) {
                bf16x8 kf[4];
#pragma unroll
                for (int mi = 0; mi < 4; mi++)
                    kf[mi] = *(const bf16x8*)&KVf[0][s][kk][mi][lane * 8];
#pragma unroll
                for (int mi = 0; mi < 4; mi++)
                    accS[mi] = __builtin_amdgcn_mfma_f32_16x16x32_bf16(kf[mi], qf[s][kk], accS[mi], 0, 0, 0);
            }

        // ---- online softmax over keys (regs+quads), per q-column (l15) ----
        float mx = accS[0][0];
#pragma unroll
        for (int mi = 0; mi < 4; mi++)
#pragma unroll
            for (int r = 0; r < 4; r++) mx = fmaxf(mx, accS[mi][r]);
        mx = fmaxf(mx, __shfl_xor(mx, 16));
        mx = fmaxf(mx, __shfl_xor(mx, 32));
        float mnew  = fmaxf(m_prev, mx);
        float alpha = __expf(m_prev - mnew);
        float p[4][4], rs = 0.f;
#pragma unroll
        for (int mi = 0; mi < 4; mi++)
#pragma unroll
            for (int r = 0; r < 4; r++) {
                float pv = __expf(accS[mi][r] - mnew);
                p[mi][r] = pv;
                rs += pv;
            }
        rs += __shfl_xor(rs, 16);
        rs += __shfl_xor(rs, 32);
        l_run  = l_run * alpha + rs;
        m_prev = mnew;

        // alpha lives lane-indexed (q=l15); accO rows are reg-indexed (q=quad*4+r)
        float alr[4];
#pragma unroll
        for (int r = 0; r < 4; r++) alr[r] = __shfl(alpha, quad * 4 + r);
#pragma unroll
        for (int s = 0; s < 2; s++)
#pragma unroll
            for (int ni = 0; ni < 4; ni++)
#pragma unroll
                for (int r = 0; r < 4; r++) accO[s][ni][r] *= alr[r];

        // ---- P[q][key] to per-wave LDS (intra-wave only; no barrier) ----
#pragma unroll
        for (int mi = 0; mi < 4; mi++)
#pragma unroll
            for (int r = 0; r < 4; r++)
                Ps[w][l15 * 72 + mi * 16 + quad * 4 + r] = (__bf16)p[mi][r];

        // ---- O_s += P @ V_s (A-frag from Ps, B-frag from Vf LDS) ----
#pragma unroll
        for (int kk = 0; kk < 2; kk++) {
            bf16x8 pa = *(const bf16x8*)&Ps[w][l15 * 72 + kk * 32 + quad * 8];
#pragma unroll
            for (int s = 0; s < 2; s++)
#pragma unroll
                for (int ni = 0; ni < 4; ni++) {
                    bf16x8 vf = *(const bf16x8*)&KVf[1][s][kk][ni][lane * 8];
                    accO[s][ni] = __builtin_amdgcn_mfma_f32_16x16x32_bf16(pa, vf, accO[s][ni], 0, 0, 0);
                }
        }
    }

    // Epilogue: accO C-layout: col(l15)=d-part, row(quad*4+r)=q. l_run lane-idx.
    float il = 1.f / l_run;
    float ilr[4];
#pragma unroll
    for (int r = 0; r < 4; r++) ilr[r] = __shfl(il, quad * 4 + r);
#pragma unroll
    for (int r = 0; r < 4; r++) {
        int tok = qt * 64 + w * 16 + quad * 4 + r;
#pragma unroll
        for (int s = 0; s < 2; s++)
#pragma unroll
            for (int ni = 0; ni < 4; ni++) {
                size_t idx = ((size_t)((s * 4 + b) * 1024 + tok)) * 768 + h * 64 + ni * 16 + l15;
                ows[idx] = (__bf16)(accO[s][ni][r] * ilr[r]);
            }
    }
}

// ---------------------------------------------------------------------------
extern "C" void kernel_launch(void* const* d_in, const int* in_sizes, int n_in,
                              void* d_out, int out_size, void* d_ws, size_t ws_size,
                              hipStream_t stream)
{
    const float* x1    = (const float*)d_in[0];
    const float* x2    = (const float*)d_in[1];
    const float* Wqkv  = (const float*)d_in[2];
    const float* bqkv  = (const float*)d_in[3];
    const float* Wproj = (const float*)d_in[4];
    const float* bproj = (const float*)d_in[5];
    float* out = (float*)d_out;

    // ws: q | k | v | pool   (4 x 6291456 bf16 = 50.33 MB, proven footprint)
    const size_t qkv_elems = (size_t)2 * 4 * 12 * 1024 * 64;   // 6,291,456
    __bf16* q_ws = (__bf16*)d_ws;
    __bf16* k_ws = q_ws + qkv_elems;
    __bf16* v_ws = k_ws + qkv_elems;
    __bf16* pool = v_ws + qkv_elems;
    __bf16* Xc  = pool;                 // 4096*768 = 3,145,728
    __bf16* Wqc = pool + 3145728;       // 2304*768 = 1,769,472
    __bf16* o_ws = pool;                // 8192*768 = 6,291,456 (after QKV)
    __bf16* Wpc = q_ws;                 // 768*768 (q dead after attn)

    // stream 0
    cvt_k<<<1536, 256, 0, stream>>>(x1, Xc, 3145728);
    cvt_k<<<864,  256, 0, stream>>>(Wqkv, Wqc, 1769472);
    gemm_qkv_s<<<dim3(18, 32), 256, 0, stream>>>(Xc, Wqc, bqkv, q_ws, k_ws, v_ws, 0);
    // stream 1 (Xc reused)
    cvt_k<<<1536, 256, 0, stream>>>(x2, Xc, 3145728);
    gemm_qkv_s<<<dim3(18, 32), 256, 0, stream>>>(Xc, Wqc, bqkv, q_ws, k_ws, v_ws, 1);
    // attention (fragment-major LDS staging, XCD-swizzled 1-D grid)
    attn_k<<<768, 256, 0, stream>>>(q_ws, k_ws, v_ws, o_ws);
    // proj
    cvt_k<<<288, 256, 0, stream>>>(Wproj, Wpc, 589824);
    gemm_proj<<<dim3(6, 64), 256, 0, stream>>>(o_ws, Wpc, bproj, out);
}